// Round 1
// baseline (567.229 us; speedup 1.0000x reference)
//
#include <hip/hip_runtime.h>
#include <hip/hip_bf16.h>

#define S_LEN 2048
#define HID 2048
#define NB 2
#define NH 16
#define NKV 8
#define DH 128
#define RQ 6
#define KG 2048
#define SCALING 0.08838834764831845f

typedef __attribute__((ext_vector_type(8))) short s16x8;
typedef __attribute__((ext_vector_type(4))) float f32x4;

__device__ __forceinline__ float bf2f(ushort u) {
    union { unsigned int i; float f; } v; v.i = ((unsigned int)u) << 16; return v.f;
}
__device__ __forceinline__ ushort f2bf(float f) {
    __hip_bfloat16 h = __float2bfloat16(f);
    return *reinterpret_cast<ushort*>(&h);
}
__device__ __forceinline__ void g2lds16(const void* g, void* l) {
    __builtin_amdgcn_global_load_lds((const __attribute__((address_space(1))) void*)g,
                                     (__attribute__((address_space(3))) void*)l, 16, 0, 0);
}

// ---------------- fp32 -> bf16 convert (vector) ----------------
__global__ void k_cvt_bf16(const float* __restrict__ in, ushort* __restrict__ out, int n4) {
    int i = blockIdx.x * 256 + threadIdx.x;
    if (i >= n4) return;
    float4 v = ((const float4*)in)[i];
    ushort4 o;
    o.x = f2bf(v.x); o.y = f2bf(v.y); o.z = f2bf(v.z); o.w = f2bf(v.w);
    ((ushort4*)out)[i] = o;
}

// ---------------- weight transpose+convert: in [K=2048][Nin] f32 -> out [(rowOff+n)][2048] bf16 ----------------
__global__ void k_transpose_w(const float* __restrict__ in, ushort* __restrict__ out, int Nin, int rowOff) {
    __shared__ ushort tile[64][66];
    int k0 = blockIdx.x * 64, n0 = blockIdx.y * 64;
    int t = threadIdx.x;
#pragma unroll
    for (int i = 0; i < 16; ++i) {
        int f = t + i * 256; int r = f >> 6, c = f & 63;
        int nn = n0 + c;
        float v = (nn < Nin) ? in[(size_t)(k0 + r) * Nin + nn] : 0.f;
        tile[r][c] = f2bf(v);
    }
    __syncthreads();
#pragma unroll
    for (int i = 0; i < 16; ++i) {
        int f = t + i * 256; int nr = f >> 6, kc = f & 63;
        int nn = n0 + nr;
        if (nn < Nin) out[(size_t)(rowOff + nn) * KG + k0 + kc] = tile[kc][nr];
    }
}

// ---------------- generic bf16 GEMM: A[M][2048] @ Bt[N][2048]^T -> C[M][ldc], 128x128 tile ----------------
__device__ __forceinline__ void stc(float* p, float v) { *p = v; }
__device__ __forceinline__ void stc(ushort* p, float v) { *p = f2bf(v); }

template<typename OutT>
__global__ __launch_bounds__(256, 2) void k_gemm(const ushort* __restrict__ A,
                                                 const ushort* __restrict__ Bt,
                                                 OutT* __restrict__ C, int ldc) {
    __shared__ ushort lA[128 * 64];
    __shared__ ushort lB[128 * 64];
    const int tid = threadIdx.x;
    const int l = tid & 63, w = tid >> 6;
    const int m0 = blockIdx.x * 128, n0 = blockIdx.y * 128;
    const int wm = w >> 1, wn = w & 1;
    f32x4 acc[4][4] = {};
    const int swz = 16 * ((tid & 7) ^ ((tid >> 3) & 7));
    const int rowbase = tid >> 3;

    for (int k0 = 0; k0 < KG; k0 += 64) {
#pragma unroll
        for (int i = 0; i < 4; ++i) {
            int row = rowbase + i * 32;
            const char* srcA = (const char*)A + (((size_t)(m0 + row) * KG + k0) * 2) + swz;
            g2lds16(srcA, (char*)lA + tid * 16 + i * 4096);
            const char* srcB = (const char*)Bt + (((size_t)(n0 + row) * KG + k0) * 2) + swz;
            g2lds16(srcB, (char*)lB + tid * 16 + i * 4096);
        }
        __syncthreads();
#pragma unroll
        for (int kk = 0; kk < 2; ++kk) {
            s16x8 af[4], bfr[4];
            const int kb = kk * 64 + (l >> 4) * 16;
#pragma unroll
            for (int mf = 0; mf < 4; ++mf) {
                int row = wm * 64 + mf * 16 + (l & 15);
                af[mf] = *(const s16x8*)((const char*)lA + row * 128 + (kb ^ ((row & 7) << 4)));
            }
#pragma unroll
            for (int nf = 0; nf < 4; ++nf) {
                int row = wn * 64 + nf * 16 + (l & 15);
                bfr[nf] = *(const s16x8*)((const char*)lB + row * 128 + (kb ^ ((row & 7) << 4)));
            }
#pragma unroll
            for (int mf = 0; mf < 4; ++mf)
#pragma unroll
                for (int nf = 0; nf < 4; ++nf)
                    acc[mf][nf] = __builtin_amdgcn_mfma_f32_16x16x32_bf16(af[mf], bfr[nf], acc[mf][nf], 0, 0, 0);
        }
        __syncthreads();
    }
#pragma unroll
    for (int mf = 0; mf < 4; ++mf)
#pragma unroll
        for (int r = 0; r < 4; ++r) {
            int row = m0 + wm * 64 + mf * 16 + (l >> 4) * 4 + r;
#pragma unroll
            for (int nf = 0; nf < 4; ++nf) {
                int col = n0 + wn * 64 + nf * 16 + (l & 15);
                stc(C + (size_t)row * ldc + col, acc[mf][nf][r]);
            }
        }
}

// ---------------- contract ranks + rope + scale for q (one Bq chunk of 4 heads) ----------------
__global__ void k_contract_q(const ushort* __restrict__ bq, const float* __restrict__ small,
                             const float* __restrict__ cosT, const float* __restrict__ sinT,
                             ushort* __restrict__ q, int chunk) {
    int srow = blockIdx.x;               // 0..4095 == b*2048 + s
    int b = srow >> 11, sl = srow & 2047;
    int t = threadIdx.x;
    int d2 = t & 63, hp = t >> 6;        // hp 0..3
    int h = chunk * 4 + hp;
    const ushort* bqr = bq + (size_t)srow * 3072 + hp * 768;
    const float* af = small + (size_t)srow * 640 + h * RQ;
    float x1 = 0.f, x2 = 0.f;
#pragma unroll
    for (int r = 0; r < RQ; ++r) {
        float a = af[r];
        x1 += a * bf2f(bqr[r * 128 + d2]);
        x2 += a * bf2f(bqr[r * 128 + 64 + d2]);
    }
    float c = cosT[sl * 64 + d2], s = sinT[sl * 64 + d2];
    float q1 = (x1 * c - x2 * s) * SCALING;
    float q2 = (x1 * s + x2 * c) * SCALING;
    size_t o = ((size_t)(b * NH + h) * S_LEN + sl) * DH + d2;
    q[o] = f2bf(q1);
    q[o + 64] = f2bf(q2);
}

// ---------------- contract ranks for k (rope) and v (write v^T) ----------------
__global__ void k_contract_kv(const float* __restrict__ small, const float* __restrict__ cosT,
                              const float* __restrict__ sinT, ushort* __restrict__ kk,
                              ushort* __restrict__ vT) {
    int srow = blockIdx.x;
    int b = srow >> 11, sl = srow & 2047;
    int t = threadIdx.x;                 // 512 threads
    int d2 = t & 63, g = t >> 6;         // g 0..7
    const float* row = small + (size_t)srow * 640;
    float k1 = 0.f, k2 = 0.f, v1 = 0.f, v2 = 0.f;
#pragma unroll
    for (int r = 0; r < 2; ++r) {
        float ak = row[96 + g * 2 + r];
        k1 += ak * row[128 + r * 128 + d2];
        k2 += ak * row[128 + r * 128 + 64 + d2];
        float av = row[112 + g * 2 + r];
        v1 += av * row[384 + r * 128 + d2];
        v2 += av * row[384 + r * 128 + 64 + d2];
    }
    float c = cosT[sl * 64 + d2], s = sinT[sl * 64 + d2];
    float kr1 = k1 * c - k2 * s, kr2 = k1 * s + k2 * c;
    size_t ko = ((size_t)(b * NKV + g) * S_LEN + sl) * DH + d2;
    kk[ko] = f2bf(kr1);
    kk[ko + 64] = f2bf(kr2);
    size_t vo = ((size_t)(b * NKV + g) * DH + d2) * S_LEN + sl;
    vT[vo] = f2bf(v1);
    vT[vo + (size_t)64 * S_LEN] = f2bf(v2);
}

// ---------------- flash attention with sliding window + tanh softcap ----------------
__global__ __launch_bounds__(256, 2) void k_attn(const ushort* __restrict__ q, const ushort* __restrict__ kk,
                                                 const ushort* __restrict__ vT, ushort* __restrict__ O) {
    __shared__ char sK[16384];   // [64 tok][128 d] bf16, swizzled
    __shared__ char sV[16384];   // [128 d][64 tok] bf16, swizzled
    __shared__ char sP[8192];    // per-wave 2KB: [16 q][64 kj] bf16, swizzled
    const int qb = blockIdx.x;   // 0..31
    const int bh = blockIdx.y;   // 0..31
    const int b = bh >> 4, h = bh & 15, g = h >> 1;
    const int tid = threadIdx.x, l = tid & 63, w = tid >> 6;
    const int qs = qb * 64;
    const int q0 = qs + w * 16;

    const ushort* qbase = q + ((size_t)(b * NH + h) * S_LEN) * DH;
    s16x8 qf[4];
    {
        const char* qrow = (const char*)(qbase + (size_t)(q0 + (l & 15)) * DH);
#pragma unroll
        for (int ds = 0; ds < 4; ++ds)
            qf[ds] = *(const s16x8*)(qrow + ds * 64 + (l >> 4) * 16);
    }
    f32x4 acc[8] = {};
    float mrow[4] = {-1e30f, -1e30f, -1e30f, -1e30f};
    float lrow[4] = {0.f, 0.f, 0.f, 0.f};

    const size_t kgbase = ((size_t)(b * NKV + g) * S_LEN) * DH * 2;
    const size_t vgbase = ((size_t)(b * NKV + g) * DH) * S_LEN * 2;

    const int jt0 = (qs > 1023) ? ((qs - 1023) >> 6) : 0;
    for (int jt = jt0; jt <= qb; ++jt) {
        // stage K tile (64 tok x 128 d) with swizzled source
#pragma unroll
        for (int i = 0; i < 4; ++i) {
            int row = (tid >> 4) + i * 16;
            int colb = (tid & 15) * 16;
            const char* src = (const char*)kk + kgbase + ((size_t)(jt * 64 + row)) * 256 + (colb ^ ((row & 7) << 4));
            g2lds16(src, sK + tid * 16 + i * 4096);
        }
        // stage V^T tile (128 d x 64 tok)
#pragma unroll
        for (int i = 0; i < 4; ++i) {
            int row = (tid >> 3) + i * 32;
            int colb = (tid & 7) * 16;
            const char* src = (const char*)vT + vgbase + (size_t)row * 4096 + (size_t)jt * 128 + (colb ^ ((row & 7) << 4));
            g2lds16(src, sV + tid * 16 + i * 4096);
        }
        __syncthreads();

        // QK^T: 16 q-rows x 64 keys per wave
        f32x4 sc[4];
#pragma unroll
        for (int ct = 0; ct < 4; ++ct) {
            f32x4 z = {};
            int row = ct * 16 + (l & 15);
#pragma unroll
            for (int ds = 0; ds < 4; ++ds) {
                int kb = ds * 64 + (l >> 4) * 16;
                s16x8 kf = *(const s16x8*)(sK + row * 256 + (kb ^ ((row & 7) << 4)));
                z = __builtin_amdgcn_mfma_f32_16x16x32_bf16(qf[ds], kf, z, 0, 0, 0);
            }
            sc[ct] = z;
        }
        // softcap + window mask
        float p[4][4];
#pragma unroll
        for (int ct = 0; ct < 4; ++ct) {
            int j = jt * 64 + ct * 16 + (l & 15);
#pragma unroll
            for (int r = 0; r < 4; ++r) {
                int i_ = qs + w * 16 + (l >> 4) * 4 + r;
                float x = sc[ct][r];
                float e = __expf(x * 0.04f);          // exp(2x/50)
                float tcap = 50.f - 100.f / (e + 1.f); // 50*tanh(x/50)
                bool ok = (j <= i_) && (i_ - j < 1024);
                p[ct][r] = ok ? tcap : -3e38f;
            }
        }
        // online softmax
#pragma unroll
        for (int r = 0; r < 4; ++r) {
            float v = fmaxf(fmaxf(p[0][r], p[1][r]), fmaxf(p[2][r], p[3][r]));
            v = fmaxf(v, __shfl_xor(v, 1));
            v = fmaxf(v, __shfl_xor(v, 2));
            v = fmaxf(v, __shfl_xor(v, 4));
            v = fmaxf(v, __shfl_xor(v, 8));
            float mnew = fmaxf(mrow[r], v);
            float f = __expf(mrow[r] - mnew);
            mrow[r] = mnew;
            float rs = 0.f;
#pragma unroll
            for (int ct = 0; ct < 4; ++ct) {
                float pe = __expf(p[ct][r] - mnew);
                p[ct][r] = pe;
                rs += pe;
            }
            rs += __shfl_xor(rs, 1); rs += __shfl_xor(rs, 2);
            rs += __shfl_xor(rs, 4); rs += __shfl_xor(rs, 8);
            lrow[r] = lrow[r] * f + rs;
#pragma unroll
            for (int dt = 0; dt < 8; ++dt) acc[dt][r] *= f;
        }
        // P -> LDS (per-wave region, bf16, swizzled)
#pragma unroll
        for (int ct = 0; ct < 4; ++ct) {
            int col = ct * 16 + (l & 15);
#pragma unroll
            for (int r = 0; r < 4; ++r) {
                int row = (l >> 4) * 4 + r;
                *(ushort*)(sP + w * 2048 + row * 128 + ((col * 2) ^ ((row & 7) << 4))) = f2bf(p[ct][r]);
            }
        }
        // PV
#pragma unroll
        for (int s2 = 0; s2 < 2; ++s2) {
            int rowp = l & 15;
            int kb = s2 * 64 + (l >> 4) * 16;
            s16x8 pf = *(const s16x8*)(sP + w * 2048 + rowp * 128 + (kb ^ ((rowp & 7) << 4)));
#pragma unroll
            for (int dt = 0; dt < 8; ++dt) {
                int d = dt * 16 + (l & 15);
                s16x8 vf = *(const s16x8*)(sV + d * 128 + (kb ^ ((d & 7) << 4)));
                acc[dt] = __builtin_amdgcn_mfma_f32_16x16x32_bf16(pf, vf, acc[dt], 0, 0, 0);
            }
        }
        __syncthreads();
    }
    // epilogue: O[b, s, h*128 + d]
#pragma unroll
    for (int r = 0; r < 4; ++r) {
        int row = qs + w * 16 + (l >> 4) * 4 + r;
        float inv = 1.f / lrow[r];
#pragma unroll
        for (int dt = 0; dt < 8; ++dt)
            O[((size_t)(b * S_LEN + row)) * HID + h * DH + dt * 16 + (l & 15)] = f2bf(acc[dt][r] * inv);
    }
}

extern "C" void kernel_launch(void* const* d_in, const int* in_sizes, int n_in,
                              void* d_out, int out_size, void* d_ws, size_t ws_size,
                              hipStream_t stream) {
    (void)in_sizes; (void)n_in; (void)out_size; (void)ws_size;
    const float* hs  = (const float*)d_in[0];
    const float* WAq = (const float*)d_in[1];
    const float* WBq = (const float*)d_in[2];
    const float* WAk = (const float*)d_in[3];
    const float* WBk = (const float*)d_in[4];
    const float* WAv = (const float*)d_in[5];
    const float* WBv = (const float*)d_in[6];
    const float* Wo  = (const float*)d_in[7];
    const float* fc  = (const float*)d_in[8];
    const float* fs  = (const float*)d_in[9];

    char* ws = (char*)d_ws;
    ushort* Xb    = (ushort*)(ws + 0);            // 4096x2048 bf16       16.78 MB
    ushort* WtS   = (ushort*)(ws + 16777216);     // 640x2048 bf16         2.62 MB
    ushort* WtBq  = (ushort*)(ws + 19398656);     // 12288x2048 bf16      50.33 MB
    ushort* WtWo  = (ushort*)(ws + 69730304);     // 2048x2048 bf16        8.39 MB
    float*  Small = (float*) (ws + 78118912);     // 4096x640 f32         10.49 MB
    ushort* BqC   = (ushort*)(ws + 88604672);     // 4096x3072 bf16       25.17 MB
    ushort* qB    = (ushort*)(ws + 113770496);    // (B,H,S,D) bf16       16.78 MB
    ushort* kB    = (ushort*)(ws + 130547712);    // (B,KV,S,D) bf16       8.39 MB
    ushort* vTB   = (ushort*)(ws + 138936320);    // (B,KV,D,S) bf16       8.39 MB
    ushort* OB    = (ushort*)(ws + 147324928);    // 4096x2048 bf16       16.78 MB

    k_cvt_bf16<<<8192, 256, 0, stream>>>(hs, Xb, 2097152);
    k_transpose_w<<<dim3(32, 2),   256, 0, stream>>>(WAq, WtS, 96, 0);
    k_transpose_w<<<dim3(32, 1),   256, 0, stream>>>(WAk, WtS, 16, 96);
    k_transpose_w<<<dim3(32, 1),   256, 0, stream>>>(WAv, WtS, 16, 112);
    k_transpose_w<<<dim3(32, 4),   256, 0, stream>>>(WBk, WtS, 256, 128);
    k_transpose_w<<<dim3(32, 4),   256, 0, stream>>>(WBv, WtS, 256, 384);
    k_transpose_w<<<dim3(32, 192), 256, 0, stream>>>(WBq, WtBq, 12288, 0);
    k_transpose_w<<<dim3(32, 32),  256, 0, stream>>>(Wo, WtWo, 2048, 0);

    k_gemm<float><<<dim3(32, 5), 256, 0, stream>>>(Xb, WtS, Small, 640);
    k_contract_kv<<<4096, 512, 0, stream>>>(Small, fc, fs, kB, vTB);

    for (int c = 0; c < 4; ++c) {
        k_gemm<ushort><<<dim3(32, 24), 256, 0, stream>>>(Xb, WtBq + (size_t)c * 3072 * KG, BqC, 3072);
        k_contract_q<<<4096, 256, 0, stream>>>(BqC, Small, fc, fs, qB, c);
    }

    k_attn<<<dim3(32, 32), 256, 0, stream>>>(qB, kB, vTB, OB);

    k_gemm<float><<<dim3(32, 16), 256, 0, stream>>>(OB, WtWo, (float*)d_out, 2048);
}

// Round 2
// 534.678 us; speedup vs baseline: 1.0609x; 1.0609x over previous
//
#include <hip/hip_runtime.h>
#include <hip/hip_bf16.h>

#define S_LEN 2048
#define HID 2048
#define NB 2
#define NH 16
#define NKV 8
#define DH 128
#define RQ 6
#define KG 2048
#define SCALING 0.08838834764831845f

typedef __attribute__((ext_vector_type(8))) short s16x8;
typedef __attribute__((ext_vector_type(4))) float f32x4;

__device__ __forceinline__ float bf2f(ushort u) {
    union { unsigned int i; float f; } v; v.i = ((unsigned int)u) << 16; return v.f;
}
__device__ __forceinline__ ushort f2bf(float f) {
    __hip_bfloat16 h = __float2bfloat16(f);
    return *reinterpret_cast<ushort*>(&h);
}
__device__ __forceinline__ void g2lds16(const void* g, void* l) {
    __builtin_amdgcn_global_load_lds((const __attribute__((address_space(1))) void*)g,
                                     (__attribute__((address_space(3))) void*)l, 16, 0, 0);
}

// ---------------- fp32 -> bf16 convert (vector) ----------------
__global__ void k_cvt_bf16(const float* __restrict__ in, ushort* __restrict__ out, int n4) {
    int i = blockIdx.x * 256 + threadIdx.x;
    if (i >= n4) return;
    float4 v = ((const float4*)in)[i];
    ushort4 o;
    o.x = f2bf(v.x); o.y = f2bf(v.y); o.z = f2bf(v.z); o.w = f2bf(v.w);
    ((ushort4*)out)[i] = o;
}

// ---------------- weight transpose+convert: in [K=2048][Nin] f32 -> out [(rowOff+n)][2048] bf16 ----------------
__global__ void k_transpose_w(const float* __restrict__ in, ushort* __restrict__ out, int Nin, int rowOff) {
    __shared__ ushort tile[64][66];
    int k0 = blockIdx.x * 64, n0 = blockIdx.y * 64;
    int t = threadIdx.x;
#pragma unroll
    for (int i = 0; i < 16; ++i) {
        int f = t + i * 256; int r = f >> 6, c = f & 63;
        int nn = n0 + c;
        float v = (nn < Nin) ? in[(size_t)(k0 + r) * Nin + nn] : 0.f;
        tile[r][c] = f2bf(v);
    }
    __syncthreads();
#pragma unroll
    for (int i = 0; i < 16; ++i) {
        int f = t + i * 256; int nr = f >> 6, kc = f & 63;
        int nn = n0 + nr;
        if (nn < Nin) out[(size_t)(rowOff + nn) * KG + k0 + kc] = tile[kc][nr];
    }
}

// ---------------- generic bf16 GEMM: A[M][2048] @ Bt[N][2048]^T -> C[M][ldc], 128x128 tile ----------------
__device__ __forceinline__ void stc(float* p, float v) { *p = v; }
__device__ __forceinline__ void stc(ushort* p, float v) { *p = f2bf(v); }

template<typename OutT>
__global__ __launch_bounds__(256, 2) void k_gemm(const ushort* __restrict__ A,
                                                 const ushort* __restrict__ Bt,
                                                 OutT* __restrict__ C, int ldc) {
    __shared__ ushort lA[128 * 64];
    __shared__ ushort lB[128 * 64];
    const int tid = threadIdx.x;
    const int l = tid & 63, w = tid >> 6;
    // bijective XCD swizzle (all grids used have nwg % 8 == 0)
    const int gx = gridDim.x;
    int flat = blockIdx.y * gx + blockIdx.x;
    const int nwg = gx * gridDim.y;
    if ((nwg & 7) == 0) {
        int qq = nwg >> 3;
        flat = (flat & 7) * qq + (flat >> 3);
    }
    const int m0 = (flat % gx) * 128, n0 = (flat / gx) * 128;
    const int wm = w >> 1, wn = w & 1;
    f32x4 acc[4][4] = {};
    const int swz = 16 * ((tid & 7) ^ ((tid >> 3) & 7));
    const int rowbase = tid >> 3;

    for (int k0 = 0; k0 < KG; k0 += 64) {
#pragma unroll
        for (int i = 0; i < 4; ++i) {
            int row = rowbase + i * 32;
            const char* srcA = (const char*)A + (((size_t)(m0 + row) * KG + k0) * 2) + swz;
            g2lds16(srcA, (char*)lA + tid * 16 + i * 4096);
            const char* srcB = (const char*)Bt + (((size_t)(n0 + row) * KG + k0) * 2) + swz;
            g2lds16(srcB, (char*)lB + tid * 16 + i * 4096);
        }
        __syncthreads();
#pragma unroll
        for (int kk = 0; kk < 2; ++kk) {
            s16x8 af[4], bfr[4];
            const int kb = kk * 64 + (l >> 4) * 16;
#pragma unroll
            for (int mf = 0; mf < 4; ++mf) {
                int row = wm * 64 + mf * 16 + (l & 15);
                af[mf] = *(const s16x8*)((const char*)lA + row * 128 + (kb ^ ((row & 7) << 4)));
            }
#pragma unroll
            for (int nf = 0; nf < 4; ++nf) {
                int row = wn * 64 + nf * 16 + (l & 15);
                bfr[nf] = *(const s16x8*)((const char*)lB + row * 128 + (kb ^ ((row & 7) << 4)));
            }
#pragma unroll
            for (int mf = 0; mf < 4; ++mf)
#pragma unroll
                for (int nf = 0; nf < 4; ++nf)
                    acc[mf][nf] = __builtin_amdgcn_mfma_f32_16x16x32_bf16(af[mf], bfr[nf], acc[mf][nf], 0, 0, 0);
        }
        __syncthreads();
    }
#pragma unroll
    for (int mf = 0; mf < 4; ++mf)
#pragma unroll
        for (int r = 0; r < 4; ++r) {
            int row = m0 + wm * 64 + mf * 16 + (l >> 4) * 4 + r;
#pragma unroll
            for (int nf = 0; nf < 4; ++nf) {
                int col = n0 + wn * 64 + nf * 16 + (l & 15);
                stc(C + (size_t)row * ldc + col, acc[mf][nf][r]);
            }
        }
}

// ---------------- contract ranks + rope + scale for q (one Bq chunk of 4 heads) ----------------
__global__ void k_contract_q(const ushort* __restrict__ bq, const float* __restrict__ small,
                             const float* __restrict__ cosT, const float* __restrict__ sinT,
                             ushort* __restrict__ q, int chunk) {
    int srow = blockIdx.x;               // 0..4095 == b*2048 + s
    int b = srow >> 11, sl = srow & 2047;
    int t = threadIdx.x;
    int d2 = t & 63, hp = t >> 6;        // hp 0..3
    int h = chunk * 4 + hp;
    const ushort* bqr = bq + (size_t)srow * 3072 + hp * 768;
    const float* af = small + (size_t)srow * 640 + h * RQ;
    float x1 = 0.f, x2 = 0.f;
#pragma unroll
    for (int r = 0; r < RQ; ++r) {
        float a = af[r];
        x1 += a * bf2f(bqr[r * 128 + d2]);
        x2 += a * bf2f(bqr[r * 128 + 64 + d2]);
    }
    float c = cosT[sl * 64 + d2], s = sinT[sl * 64 + d2];
    float q1 = (x1 * c - x2 * s) * SCALING;
    float q2 = (x1 * s + x2 * c) * SCALING;
    size_t o = ((size_t)(b * NH + h) * S_LEN + sl) * DH + d2;
    q[o] = f2bf(q1);
    q[o + 64] = f2bf(q2);
}

// ---------------- contract ranks for k (rope) and v (write v^T) ----------------
__global__ void k_contract_kv(const float* __restrict__ small, const float* __restrict__ cosT,
                              const float* __restrict__ sinT, ushort* __restrict__ kk,
                              ushort* __restrict__ vT) {
    int srow = blockIdx.x;
    int b = srow >> 11, sl = srow & 2047;
    int t = threadIdx.x;                 // 512 threads
    int d2 = t & 63, g = t >> 6;         // g 0..7
    const float* row = small + (size_t)srow * 640;
    float k1 = 0.f, k2 = 0.f, v1 = 0.f, v2 = 0.f;
#pragma unroll
    for (int r = 0; r < 2; ++r) {
        float ak = row[96 + g * 2 + r];
        k1 += ak * row[128 + r * 128 + d2];
        k2 += ak * row[128 + r * 128 + 64 + d2];
        float av = row[112 + g * 2 + r];
        v1 += av * row[384 + r * 128 + d2];
        v2 += av * row[384 + r * 128 + 64 + d2];
    }
    float c = cosT[sl * 64 + d2], s = sinT[sl * 64 + d2];
    float kr1 = k1 * c - k2 * s, kr2 = k1 * s + k2 * c;
    size_t ko = ((size_t)(b * NKV + g) * S_LEN + sl) * DH + d2;
    kk[ko] = f2bf(kr1);
    kk[ko + 64] = f2bf(kr2);
    size_t vo = ((size_t)(b * NKV + g) * DH + d2) * S_LEN + sl;
    vT[vo] = f2bf(v1);
    vT[vo + (size_t)64 * S_LEN] = f2bf(v2);
}

// ---------------- flash attention with sliding window + tanh softcap ----------------
// Fixed-shift softmax: scores are tanh-capped at <= 50, so shift m = 50 is a valid
// (>= max) softmax shift. Removes running max, acc rescale, and per-tile cross-lane
// reductions entirely; lrow reduced once after the KV loop.
__global__ __launch_bounds__(256, 2) void k_attn(const ushort* __restrict__ q, const ushort* __restrict__ kk,
                                                 const ushort* __restrict__ vT, ushort* __restrict__ O) {
    __shared__ char sK[16384];   // [64 tok][128 d] bf16, swizzled
    __shared__ char sV[16384];   // [128 d][64 tok] bf16, swizzled
    __shared__ char sP[8192];    // per-wave 2KB: [16 q][64 kj] bf16, swizzled
    const int qb = 31 - blockIdx.x;   // heavy blocks (most KV tiles) first
    const int bh = blockIdx.y;   // 0..31
    const int b = bh >> 4, h = bh & 15, g = h >> 1;
    const int tid = threadIdx.x, l = tid & 63, w = tid >> 6;
    const int qs = qb * 64;
    const int q0 = qs + w * 16;

    const ushort* qbase = q + ((size_t)(b * NH + h) * S_LEN) * DH;
    s16x8 qf[4];
    {
        const char* qrow = (const char*)(qbase + (size_t)(q0 + (l & 15)) * DH);
#pragma unroll
        for (int ds = 0; ds < 4; ++ds)
            qf[ds] = *(const s16x8*)(qrow + ds * 64 + (l >> 4) * 16);
    }
    f32x4 acc[8] = {};
    float lrow[4] = {0.f, 0.f, 0.f, 0.f};

    const size_t kgbase = ((size_t)(b * NKV + g) * S_LEN) * DH * 2;
    const size_t vgbase = ((size_t)(b * NKV + g) * DH) * S_LEN * 2;

    const int jt0 = (qs > 1023) ? ((qs - 1023) >> 6) : 0;
    for (int jt = jt0; jt <= qb; ++jt) {
        // stage K tile (64 tok x 128 d) with swizzled source
#pragma unroll
        for (int i = 0; i < 4; ++i) {
            int row = (tid >> 4) + i * 16;
            int colb = (tid & 15) * 16;
            const char* src = (const char*)kk + kgbase + ((size_t)(jt * 64 + row)) * 256 + (colb ^ ((row & 7) << 4));
            g2lds16(src, sK + tid * 16 + i * 4096);
        }
        // stage V^T tile (128 d x 64 tok)
#pragma unroll
        for (int i = 0; i < 4; ++i) {
            int row = (tid >> 3) + i * 32;
            int colb = (tid & 7) * 16;
            const char* src = (const char*)vT + vgbase + (size_t)row * 4096 + (size_t)jt * 128 + (colb ^ ((row & 7) << 4));
            g2lds16(src, sV + tid * 16 + i * 4096);
        }
        __syncthreads();

        // QK^T: 16 q-rows x 64 keys per wave
        f32x4 sc[4];
#pragma unroll
        for (int ct = 0; ct < 4; ++ct) {
            f32x4 z = {};
            int row = ct * 16 + (l & 15);
#pragma unroll
            for (int ds = 0; ds < 4; ++ds) {
                int kb = ds * 64 + (l >> 4) * 16;
                s16x8 kf = *(const s16x8*)(sK + row * 256 + (kb ^ ((row & 7) << 4)));
                z = __builtin_amdgcn_mfma_f32_16x16x32_bf16(qf[ds], kf, z, 0, 0, 0);
            }
            sc[ct] = z;
        }
        // softcap + window mask + fixed-shift exp: p = exp(50*tanh(x/50) - 50)
        //   = exp(-100/(exp(2x/50)+1));  masked -> 0
        float p[4][4];
#pragma unroll
        for (int ct = 0; ct < 4; ++ct) {
            int j = jt * 64 + ct * 16 + (l & 15);
#pragma unroll
            for (int r = 0; r < 4; ++r) {
                int i_ = qs + w * 16 + (l >> 4) * 4 + r;
                float x = sc[ct][r];
                float e = __expf(x * 0.04f);            // exp(2x/50)
                float pe = __expf(-100.f / (e + 1.f));  // exp(tcap - 50)
                bool ok = (j <= i_) && (i_ - j < 1024);
                pe = ok ? pe : 0.f;
                p[ct][r] = pe;
                lrow[r] += pe;
            }
        }
        // P -> LDS (per-wave region, bf16, swizzled)
#pragma unroll
        for (int ct = 0; ct < 4; ++ct) {
            int col = ct * 16 + (l & 15);
#pragma unroll
            for (int r = 0; r < 4; ++r) {
                int row = (l >> 4) * 4 + r;
                *(ushort*)(sP + w * 2048 + row * 128 + ((col * 2) ^ ((row & 7) << 4))) = f2bf(p[ct][r]);
            }
        }
        // PV
#pragma unroll
        for (int s2 = 0; s2 < 2; ++s2) {
            int rowp = l & 15;
            int kb = s2 * 64 + (l >> 4) * 16;
            s16x8 pf = *(const s16x8*)(sP + w * 2048 + rowp * 128 + (kb ^ ((rowp & 7) << 4)));
#pragma unroll
            for (int dt = 0; dt < 8; ++dt) {
                int d = dt * 16 + (l & 15);
                s16x8 vf = *(const s16x8*)(sV + d * 128 + (kb ^ ((d & 7) << 4)));
                acc[dt] = __builtin_amdgcn_mfma_f32_16x16x32_bf16(pf, vf, acc[dt], 0, 0, 0);
            }
        }
        __syncthreads();
    }
    // final cross-lane reduce of lrow (sum over the 16 lanes holding this row's keys)
#pragma unroll
    for (int r = 0; r < 4; ++r) {
        float rs = lrow[r];
        rs += __shfl_xor(rs, 1); rs += __shfl_xor(rs, 2);
        rs += __shfl_xor(rs, 4); rs += __shfl_xor(rs, 8);
        lrow[r] = rs;
    }
    // epilogue: O[b, s, h*128 + d]
#pragma unroll
    for (int r = 0; r < 4; ++r) {
        int row = qs + w * 16 + (l >> 4) * 4 + r;
        float inv = 1.f / lrow[r];
#pragma unroll
        for (int dt = 0; dt < 8; ++dt)
            O[((size_t)(b * S_LEN + row)) * HID + h * DH + dt * 16 + (l & 15)] = f2bf(acc[dt][r] * inv);
    }
}

extern "C" void kernel_launch(void* const* d_in, const int* in_sizes, int n_in,
                              void* d_out, int out_size, void* d_ws, size_t ws_size,
                              hipStream_t stream) {
    (void)in_sizes; (void)n_in; (void)out_size; (void)ws_size;
    const float* hs  = (const float*)d_in[0];
    const float* WAq = (const float*)d_in[1];
    const float* WBq = (const float*)d_in[2];
    const float* WAk = (const float*)d_in[3];
    const float* WBk = (const float*)d_in[4];
    const float* WAv = (const float*)d_in[5];
    const float* WBv = (const float*)d_in[6];
    const float* Wo  = (const float*)d_in[7];
    const float* fc  = (const float*)d_in[8];
    const float* fs  = (const float*)d_in[9];

    char* ws = (char*)d_ws;
    ushort* Xb    = (ushort*)(ws + 0);            // 4096x2048 bf16       16.78 MB
    ushort* WtS   = (ushort*)(ws + 16777216);     // 640x2048 bf16         2.62 MB
    ushort* WtBq  = (ushort*)(ws + 19398656);     // 12288x2048 bf16      50.33 MB
    ushort* WtWo  = (ushort*)(ws + 69730304);     // 2048x2048 bf16        8.39 MB
    float*  Small = (float*) (ws + 78118912);     // 4096x640 f32         10.49 MB
    ushort* BqC   = (ushort*)(ws + 88604672);     // 4096x3072 bf16       25.17 MB
    ushort* qB    = (ushort*)(ws + 113770496);    // (B,H,S,D) bf16       16.78 MB
    ushort* kB    = (ushort*)(ws + 130547712);    // (B,KV,S,D) bf16       8.39 MB
    ushort* vTB   = (ushort*)(ws + 138936320);    // (B,KV,D,S) bf16       8.39 MB
    ushort* OB    = (ushort*)(ws + 147324928);    // 4096x2048 bf16       16.78 MB

    k_cvt_bf16<<<8192, 256, 0, stream>>>(hs, Xb, 2097152);
    k_transpose_w<<<dim3(32, 2),   256, 0, stream>>>(WAq, WtS, 96, 0);
    k_transpose_w<<<dim3(32, 1),   256, 0, stream>>>(WAk, WtS, 16, 96);
    k_transpose_w<<<dim3(32, 1),   256, 0, stream>>>(WAv, WtS, 16, 112);
    k_transpose_w<<<dim3(32, 4),   256, 0, stream>>>(WBk, WtS, 256, 128);
    k_transpose_w<<<dim3(32, 4),   256, 0, stream>>>(WBv, WtS, 256, 384);
    k_transpose_w<<<dim3(32, 192), 256, 0, stream>>>(WBq, WtBq, 12288, 0);
    k_transpose_w<<<dim3(32, 32),  256, 0, stream>>>(Wo, WtWo, 2048, 0);

    k_gemm<float><<<dim3(32, 5), 256, 0, stream>>>(Xb, WtS, Small, 640);
    k_contract_kv<<<4096, 512, 0, stream>>>(Small, fc, fs, kB, vTB);

    for (int c = 0; c < 4; ++c) {
        k_gemm<ushort><<<dim3(32, 24), 256, 0, stream>>>(Xb, WtBq + (size_t)c * 3072 * KG, BqC, 3072);
        k_contract_q<<<4096, 256, 0, stream>>>(BqC, Small, fc, fs, qB, c);
    }

    k_attn<<<dim3(32, 32), 256, 0, stream>>>(qB, kB, vTB, OB);

    k_gemm<float><<<dim3(32, 16), 256, 0, stream>>>(OB, WtWo, (float*)d_out, 2048);
}